// Round 1
// 448.307 us; speedup vs baseline: 1.0725x; 1.0725x over previous
//
#include <hip/hip_runtime.h>
#include <hip/hip_fp16.h>
#include <math.h>

typedef _Float16 f16;
typedef _Float16 half8_t __attribute__((ext_vector_type(8)));
typedef _Float16 half2_t __attribute__((ext_vector_type(2)));
typedef __fp16   fp16x2  __attribute__((ext_vector_type(2)));
typedef float    float4_t __attribute__((ext_vector_type(4)));

// Converted weights (f16), written once per call by convert_w_kernel.
__device__ f16 Wh[1024 * 1024];

__device__ __forceinline__ void gl_lds16(const void* g, void* l) {
    __builtin_amdgcn_global_load_lds(
        (const __attribute__((address_space(1))) void*)g,
        (__attribute__((address_space(3))) void*)l,
        16, 0, 0);
}

__device__ __forceinline__ half2_t pkrtz(float a, float b) {
    fp16x2 r = __builtin_amdgcn_cvt_pkrtz(a, b);
    return __builtin_bit_cast(half2_t, r);
}

__device__ __forceinline__ float fdot2(half2_t a, half2_t b, float c) {
    return __builtin_amdgcn_fdot2(__builtin_bit_cast(fp16x2, a),
                                  __builtin_bit_cast(fp16x2, b), c, false);
}

__device__ __forceinline__ half8_t cvt8(float4_t lo, float4_t hi) {
    half2_t p0 = pkrtz(lo[0], lo[1]);
    half2_t p1 = pkrtz(lo[2], lo[3]);
    half2_t p2 = pkrtz(hi[0], hi[1]);
    half2_t p3 = pkrtz(hi[2], hi[3]);
    half8_t r;
    r[0] = p0[0]; r[1] = p0[1]; r[2] = p1[0]; r[3] = p1[1];
    r[4] = p2[0]; r[5] = p2[1]; r[6] = p3[0]; r[7] = p3[1];
    return r;
}

__global__ __launch_bounds__(256) void convert_w_kernel(const float* __restrict__ W) {
    const int i = (blockIdx.x * 256 + threadIdx.x) * 8;
    const float4_t a = *(const float4_t*)(W + i);
    const float4_t b = *(const float4_t*)(W + i + 4);
    half8_t h;  // RTN conversion (accuracy; this kernel is cold)
#pragma unroll
    for (int t = 0; t < 4; ++t) h[t] = (f16)a[t];
#pragma unroll
    for (int t = 0; t < 4; ++t) h[4 + t] = (f16)b[t];
    *(half8_t*)(Wh + i) = h;
}

// C[m,n] = sum_k A[m,k] * W[n,k] + bias[n].  M=16384, K=N=1024.
// BK=64 (m97 structure): 32 MFMAs per wave per barrier pair -> half the
// vmcnt(0)+barrier drains of the BK=32 version.  B-tile staged from Wh (f16)
// via global_load_lds; A staged raw f32 (TA=float, converted at fragment read)
// or f16 directly.  LDS rows are 128B (f16) / 256B (f32):
//   f16: slot = chunk ^ (row&7)   -> 2-way bank alias (free)
//   f32: slot = chunk ^ (row&15)  -> conflict-free
template <typename TA, typename TC>
__device__ __forceinline__ void gemm_tile(
    const TA* __restrict__ A, const float* __restrict__ bias,
    TC* __restrict__ C)
{
    constexpr int K = 1024, N = 1024;
    constexpr bool AF32 = (sizeof(TA) == 4);
    __shared__ __align__(16) char smem[(AF32 ? 32768 : 16384) + 16384];
    float* Asf = (float*)smem;
    f16*   Ash = (f16*)smem;
    f16*   Bsh = (f16*)(smem + (AF32 ? 32768 : 16384));

    const int tid  = threadIdx.x;
    const int lane = tid & 63;
    const int wave = tid >> 6;
    const int wm = (wave >> 1) << 6;
    const int wn = (wave & 1) << 6;
    const int row0 = blockIdx.x * 128;
    const int col0 = blockIdx.y * 128;
    const int lrow = lane & 15;
    const int kq   = lane >> 4;  // 0..3, fragment k-chunk

    float4_t acc[4][4];
#pragma unroll
    for (int i = 0; i < 4; ++i)
#pragma unroll
        for (int j = 0; j < 4; ++j)
            acc[i][j] = (float4_t){0.f, 0.f, 0.f, 0.f};

    for (int kt = 0; kt < K; kt += 64) {
        // Stage B (Wh, f16): 128 rows x 64 halves = 1024 x 16B chunks.
        // LDS slot s at row r holds logical chunk s ^ (r&7).
#pragma unroll
        for (int it = 0; it < 4; ++it) {
            const int ch = tid + it * 256;
            const int r = ch >> 3, s = ch & 7;
            const f16* src = Wh + (size_t)(col0 + r) * K + kt + ((s ^ (r & 7)) << 3);
            gl_lds16(src, Bsh + ch * 8);
        }
        if constexpr (AF32) {
            // A f32: 128 rows x 64 floats = 2048 x 16B chunks; slot s holds s ^ (r&15).
#pragma unroll
            for (int it = 0; it < 8; ++it) {
                const int ch = tid + it * 256;
                const int r = ch >> 4, s = ch & 15;
                const float* src = (const float*)A + (size_t)(row0 + r) * K + kt + ((s ^ (r & 15)) << 2);
                gl_lds16(src, Asf + ch * 4);
            }
        } else {
#pragma unroll
            for (int it = 0; it < 4; ++it) {
                const int ch = tid + it * 256;
                const int r = ch >> 3, s = ch & 7;
                const f16* src = (const f16*)A + (size_t)(row0 + r) * K + kt + ((s ^ (r & 7)) << 3);
                gl_lds16(src, Ash + ch * 8);
            }
        }
        __syncthreads();

#pragma unroll
        for (int ks = 0; ks < 2; ++ks) {
            half8_t af[4], bf[4];
#pragma unroll
            for (int i = 0; i < 4; ++i) {
                const int m = wm + i * 16 + lrow;
                if constexpr (AF32) {
                    const int c0 = ks * 8 + kq * 2;
                    const float4_t lo = *(const float4_t*)(Asf + m * 64 + ((c0 ^ (m & 15)) << 2));
                    const float4_t hi = *(const float4_t*)(Asf + m * 64 + (((c0 + 1) ^ (m & 15)) << 2));
                    af[i] = cvt8(lo, hi);
                } else {
                    af[i] = *(const half8_t*)(Ash + m * 64 + (((ks * 4 + kq) ^ (m & 7)) << 3));
                }
            }
#pragma unroll
            for (int j = 0; j < 4; ++j) {
                const int n = wn + j * 16 + lrow;
                bf[j] = *(const half8_t*)(Bsh + n * 64 + (((ks * 4 + kq) ^ (n & 7)) << 3));
            }
#pragma unroll
            for (int i = 0; i < 4; ++i)
#pragma unroll
                for (int j = 0; j < 4; ++j)
                    acc[i][j] = __builtin_amdgcn_mfma_f32_16x16x32_f16(af[i], bf[j], acc[i][j], 0, 0, 0);
        }
        __syncthreads();
    }

    // Epilogue (proven in round 1): C/D layout col=lane&15, row=(lane>>4)*4+reg
    const int ccol  = lane & 15;
    const int rbase = (lane >> 4) << 2;
#pragma unroll
    for (int j = 0; j < 4; ++j) {
        const int gcol = col0 + wn + j * 16 + ccol;
        const float bv = bias[gcol];
#pragma unroll
        for (int i = 0; i < 4; ++i) {
#pragma unroll
            for (int r = 0; r < 4; ++r) {
                const int grow = row0 + wm + i * 16 + rbase + r;
                C[(size_t)grow * N + gcol] = (TC)(acc[i][j][r] + bv);
            }
        }
    }
}

template <typename TA, typename TC>
__global__ __launch_bounds__(256) void gemm_kernel(
    const TA* __restrict__ A, const float* __restrict__ bias,
    TC* __restrict__ C)
{
    gemm_tile<TA, TC>(A, bias, C);
}

// Fused q/k/v projection: same W, independent outputs -> one dispatch,
// blockIdx.z selects the input/output pair (kills 2 dispatch tails).
__global__ __launch_bounds__(256) void gemm_proj_kernel(
    const float* __restrict__ q, const float* __restrict__ k,
    const float* __restrict__ v, const float* __restrict__ bias,
    f16* __restrict__ cq, f16* __restrict__ ck, f16* __restrict__ cv)
{
    const int z = blockIdx.z;
    const float* A = (z == 0) ? q : (z == 1) ? k : v;
    f16*         C = (z == 0) ? cq : (z == 1) ? ck : cv;
    gemm_tile<float, f16>(A, bias, C);
}

// One wave per (b,s). lane = d owns a full softmax row (no cross-lane ops).
// K staged transposed [e][h] (rows padded to 24 halves = 48B, 16B-aligned),
// V staged straight [h][e] (rows padded to 72 halves = 144B). Both f16.
// QK and PV use v_dot2_f32_f16 with f32 accumulation.
__global__ __launch_bounds__(256) void attn_kernel(
    const f16* __restrict__ pq, const f16* __restrict__ pk,
    const f16* __restrict__ pv, f16* __restrict__ outp)
{
    __shared__ __align__(16) f16 Ks[4][64][24];
    __shared__ __align__(16) f16 Vs[4][16][72];
    const int lane = threadIdx.x & 63;
    const int wave = threadIdx.x >> 6;
    const int p = blockIdx.x * 4 + wave;
    const int b = p >> 11;   // / 2048
    const int s = p & 2047;
    const f16* qptr = pq + (size_t)p * 1024;
    const f16* kptr = pk + (size_t)p * 1024;
    const f16* vptr = pv + (size_t)p * 1024;

    // Stage: lane holds global halves [lane*16, lane*16+16) = h = lane>>2,
    // e in [(lane&3)*16, +16).
    {
        const int h  = lane >> 2;
        const int e0 = (lane & 3) << 4;
        const half8_t k0 = *(const half8_t*)(kptr + lane * 16);
        const half8_t k1 = *(const half8_t*)(kptr + lane * 16 + 8);
#pragma unroll
        for (int t = 0; t < 8; ++t) {
            Ks[wave][e0 + t][h]     = k0[t];
            Ks[wave][e0 + 8 + t][h] = k1[t];
        }
        const half8_t v0 = *(const half8_t*)(vptr + lane * 16);
        const half8_t v1 = *(const half8_t*)(vptr + lane * 16 + 8);
        *(half8_t*)&Vs[wave][h][e0]     = v0;
        *(half8_t*)&Vs[wave][h][e0 + 8] = v1;
    }
    // Q pairs: qp2[h2] = (Q[2h2][d], Q[2h2+1][d]), d = lane (h-major strided loads)
    half2_t qp2[8];
#pragma unroll
    for (int h2 = 0; h2 < 8; ++h2) {
        half2_t t;
        t[0] = qptr[(2 * h2) * 64 + lane];
        t[1] = qptr[(2 * h2 + 1) * 64 + lane];
        qp2[h2] = t;
    }
    __syncthreads();

    // logits[d=lane][e] = sum_h Q[h][d] K[h][e]
    float a[64];
#pragma unroll
    for (int e = 0; e < 64; ++e) {
        const half8_t* kr = (const half8_t*)&Ks[wave][e][0];
        const half8_t ka = kr[0];
        const half8_t kb = kr[1];
        float acc = 0.f;
#pragma unroll
        for (int t = 0; t < 4; ++t) {
            half2_t k2a; k2a[0] = ka[2 * t]; k2a[1] = ka[2 * t + 1];
            half2_t k2b; k2b[0] = kb[2 * t]; k2b[1] = kb[2 * t + 1];
            acc = fdot2(qp2[t], k2a, acc);
            acc = fdot2(qp2[4 + t], k2b, acc);
        }
        a[e] = acc;
    }

    // softmax over e (scale 1/sqrt(64) folded into exp arg)
    float m = a[0];
#pragma unroll
    for (int e = 1; e < 64; ++e) m = fmaxf(m, a[e]);
    float sum = 0.f;
#pragma unroll
    for (int e = 0; e < 64; ++e) {
        const float t = __expf((a[e] - m) * 0.125f);
        a[e] = t;
        sum += t;
    }
    const float inv = 1.f / sum;

    half2_t pk2[32];
#pragma unroll
    for (int e2 = 0; e2 < 32; ++e2)
        pk2[e2] = pkrtz(a[2 * e2], a[2 * e2 + 1]);

    // out[d][h] = inv * sum_e p[d][e] V[h][e]
    float o[16];
#pragma unroll
    for (int h = 0; h < 16; ++h) {
        const half8_t* vr = (const half8_t*)&Vs[wave][h][0];
        float acc = 0.f;
#pragma unroll
        for (int q8 = 0; q8 < 8; ++q8) {
            const half8_t vv = vr[q8];
#pragma unroll
            for (int t = 0; t < 4; ++t) {
                half2_t v2; v2[0] = vv[2 * t]; v2[1] = vv[2 * t + 1];
                acc = fdot2(pk2[q8 * 4 + t], v2, acc);
            }
        }
        o[h] = acc;
    }

    half8_t o0, o1;
#pragma unroll
    for (int h = 0; h < 8; ++h) o0[h] = (f16)(o[h] * inv);
#pragma unroll
    for (int h = 0; h < 8; ++h) o1[h] = (f16)(o[8 + h] * inv);
    // permuted output layout (B, D, S, H) = final linear's flat row-major input
    f16* dst = outp + ((size_t)(b * 64 + lane) * 2048 + s) * 16;
    *(half8_t*)dst       = o0;
    *(half8_t*)(dst + 8) = o1;
}

extern "C" void kernel_launch(void* const* d_in, const int* in_sizes, int n_in,
                              void* d_out, int out_size, void* d_ws, size_t ws_size,
                              hipStream_t stream)
{
    const float* q    = (const float*)d_in[0];
    const float* k    = (const float*)d_in[1];
    const float* v    = (const float*)d_in[2];
    const float* W    = (const float*)d_in[3];
    const float* bias = (const float*)d_in[4];
    float* out = (float*)d_out;

    const int M = 16384;
    const size_t elems = (size_t)M * 1024;

    // ws: projq (32MB f16) + attn_out (32MB f16). projk/projv parked inside
    // d_out (64MB fp32), consumed by attn before the final GEMM overwrites it.
    f16* projq = (f16*)d_ws;
    f16* attn  = projq + elems;
    f16* projk = (f16*)d_out;
    f16* projv = projk + elems;

    convert_w_kernel<<<512, 256, 0, stream>>>(W);

    dim3 gridp(M / 128, 1024 / 128, 3);  // fused q/k/v projections
    gemm_proj_kernel<<<gridp, 256, 0, stream>>>(q, k, v, bias, projq, projk, projv);
    attn_kernel<<<M / 4, 256, 0, stream>>>(projq, projk, projv, attn);
    dim3 grid(M / 128, 1024 / 128);
    gemm_kernel<f16, float><<<grid, 256, 0, stream>>>(attn, bias, out);
}

// Round 2
// 427.144 us; speedup vs baseline: 1.1256x; 1.0495x over previous
//
#include <hip/hip_runtime.h>
#include <hip/hip_fp16.h>
#include <math.h>

typedef _Float16 f16;
typedef _Float16 half8_t __attribute__((ext_vector_type(8)));
typedef _Float16 half2_t __attribute__((ext_vector_type(2)));
typedef __fp16   fp16x2  __attribute__((ext_vector_type(2)));
typedef float    float4_t __attribute__((ext_vector_type(4)));

// Converted weights (f16), written once per call by convert_w_kernel.
__device__ f16 Wh[1024 * 1024];

__device__ __forceinline__ void gl_lds16(const void* g, void* l) {
    __builtin_amdgcn_global_load_lds(
        (const __attribute__((address_space(1))) void*)g,
        (__attribute__((address_space(3))) void*)l,
        16, 0, 0);
}

__device__ __forceinline__ half2_t pkrtz(float a, float b) {
    fp16x2 r = __builtin_amdgcn_cvt_pkrtz(a, b);
    return __builtin_bit_cast(half2_t, r);
}

__device__ __forceinline__ float fdot2(half2_t a, half2_t b, float c) {
    return __builtin_amdgcn_fdot2(__builtin_bit_cast(fp16x2, a),
                                  __builtin_bit_cast(fp16x2, b), c, false);
}

__device__ __forceinline__ half8_t cvt8(float4_t lo, float4_t hi) {
    half2_t p0 = pkrtz(lo[0], lo[1]);
    half2_t p1 = pkrtz(lo[2], lo[3]);
    half2_t p2 = pkrtz(hi[0], hi[1]);
    half2_t p3 = pkrtz(hi[2], hi[3]);
    half8_t r;
    r[0] = p0[0]; r[1] = p0[1]; r[2] = p1[0]; r[3] = p1[1];
    r[4] = p2[0]; r[5] = p2[1]; r[6] = p3[0]; r[7] = p3[1];
    return r;
}

__global__ __launch_bounds__(256) void convert_w_kernel(const float* __restrict__ W) {
    const int i = (blockIdx.x * 256 + threadIdx.x) * 8;
    const float4_t a = *(const float4_t*)(W + i);
    const float4_t b = *(const float4_t*)(W + i + 4);
    half8_t h;  // RTN conversion (accuracy; this kernel is cold)
#pragma unroll
    for (int t = 0; t < 4; ++t) h[t] = (f16)a[t];
#pragma unroll
    for (int t = 0; t < 4; ++t) h[4 + t] = (f16)b[t];
    *(half8_t*)(Wh + i) = h;
}

// ---------------------------------------------------------------------------
// 256x256 tile, BK=64, 8 waves (512 thr), double-buffered LDS (128 KB),
// raw s_barrier + counted vmcnt (never drained in the main loop for f16-A;
// within-iteration covered waits for f32-A reg-staging).  LDS chunk swizzle:
// 16B slot s at row r holds logical chunk s ^ (r&7) -> fragment ds_read_b128
// is bank-uniform (proven 0-conflict in round 1).
// Wave layout: wr = wave>>2 (2 row-waves x 128 rows), wc = wave&3 (4 col-waves
// x 64 cols).  Per wave: acc[8][4] 16x16 fragments, 64 MFMAs per K-tile.
// ---------------------------------------------------------------------------

__device__ __forceinline__ void stage16(const f16* __restrict__ base, f16* dst,
                                        int tid, int kt) {
#pragma unroll
    for (int it = 0; it < 4; ++it) {
        const int ch = tid + it * 512;
        const int r = ch >> 3, s = ch & 7;
        gl_lds16(base + (size_t)r * 1024 + kt + ((s ^ (r & 7)) << 3), dst + ch * 8);
    }
}

__device__ __forceinline__ void loadA32(const float* __restrict__ base, int tid,
                                        int kt, int itbase, float4_t g[4]) {
#pragma unroll
    for (int it = 0; it < 2; ++it) {
        const int ch = tid + (itbase + it) * 512;
        const int r = ch >> 3, s = ch & 7;
        const float* p = base + (size_t)r * 1024 + kt + ((s ^ (r & 7)) << 3);
        g[2 * it]     = *(const float4_t*)p;
        g[2 * it + 1] = *(const float4_t*)(p + 4);
    }
}

__device__ __forceinline__ void writeA32(f16* dst, int tid, int itbase,
                                         const float4_t g[4]) {
#pragma unroll
    for (int it = 0; it < 2; ++it) {
        const int ch = tid + (itbase + it) * 512;
        *(half8_t*)(dst + ch * 8) = cvt8(g[2 * it], g[2 * it + 1]);
    }
}

template <typename TA, typename TC>
__device__ __forceinline__ void gemm_tile256(const TA* __restrict__ A,
                                             const float* __restrict__ bias,
                                             TC* __restrict__ C) {
    constexpr int K = 1024, N = 1024, NT = 16;  // NT = K/64
    constexpr bool AF32 = (sizeof(TA) == 4);
    __shared__ __align__(16) f16 smem[65536];  // 128 KB
    f16* const Asb = smem;          // [2][16384]
    f16* const Bsb = smem + 32768;  // [2][16384]

    const int tid  = threadIdx.x;
    const int lane = tid & 63;
    const int wave = tid >> 6;
    const int wr   = wave >> 2;  // 0..1
    const int wc   = wave & 3;   // 0..3
    const int lrow = lane & 15;
    const int kq   = lane >> 4;  // 0..3
    const int row0 = blockIdx.x * 256;
    const int col0 = blockIdx.y * 256;

    const f16*   Ag16 = nullptr;
    const float* Ag32 = nullptr;
    if constexpr (AF32) Ag32 = (const float*)A + (size_t)row0 * K;
    else                Ag16 = (const f16*)A + (size_t)row0 * K;
    const f16* const Bg = Wh + (size_t)col0 * K;

    float4_t acc[8][4];
#pragma unroll
    for (int i = 0; i < 8; ++i)
#pragma unroll
        for (int j = 0; j < 4; ++j)
            acc[i][j] = (float4_t){0.f, 0.f, 0.f, 0.f};

    // ---- prologue: tile 0 into buffer 0 (loads left in flight for f16)
    if constexpr (AF32) {
        stage16(Bg, Bsb, tid, 0);
        float4_t g0[4], g1[4];
        loadA32(Ag32, tid, 0, 0, g0);
        loadA32(Ag32, tid, 0, 2, g1);
        writeA32(Asb, tid, 0, g0);
        writeA32(Asb, tid, 2, g1);
        asm volatile("s_waitcnt vmcnt(0)" ::: "memory");   // B gl_lds landed
        asm volatile("s_waitcnt lgkmcnt(0)" ::: "memory"); // A ds_writes landed
    } else {
        stage16(Ag16, Asb, tid, 0);
        stage16(Bg, Bsb, tid, 0);
    }

    for (int u = 0; u < NT; ++u) {
        const int cur = u & 1;
        const f16* const Ac = Asb + (cur << 14);
        const f16* const Bc = Bsb + (cur << 14);
        f16* const An = Asb + ((cur ^ 1) << 14);
        f16* const Bn = Bsb + ((cur ^ 1) << 14);
        const int kn = ((u + 1) & (NT - 1)) * 64;  // last iter: dead re-stage of tile 0

        // issue next-tile staging (into the buffer freed at the previous barrier)
        float4_t ga[4];
        stage16(Bg, Bn, tid, kn);                 // 4 gl_lds
        if constexpr (AF32) {
            loadA32(Ag32, tid, kn, 0, ga);        // 4 dwordx4 (first A half)
        } else {
            stage16(Ag16, An, tid, kn);           // 4 gl_lds
        }
        // wait: the 8 newest vmem ops are tile u+1's; everything older (tile u)
        // must be complete.  Then sync so ALL waves' tile-u staging is visible.
        asm volatile("s_waitcnt vmcnt(8)" ::: "memory");
        __builtin_amdgcn_s_barrier();

        // B fragments for the whole tile (8 x ds_read_b128, live both phases)
        half8_t bfv[4][2];
#pragma unroll
        for (int j = 0; j < 4; ++j) {
            const int n = wc * 64 + j * 16 + lrow;
#pragma unroll
            for (int ks = 0; ks < 2; ++ks)
                bfv[j][ks] = *(const half8_t*)(Bc + n * 64 + (((ks * 4 + kq) ^ (n & 7)) << 3));
        }

        // ---- phase 0: m-fragments 0..3
        {
            half8_t afv[4][2];
#pragma unroll
            for (int i = 0; i < 4; ++i) {
                const int m = wr * 128 + i * 16 + lrow;
#pragma unroll
                for (int ks = 0; ks < 2; ++ks)
                    afv[i][ks] = *(const half8_t*)(Ac + m * 64 + (((ks * 4 + kq) ^ (m & 7)) << 3));
            }
            __builtin_amdgcn_s_setprio(1);
#pragma unroll
            for (int i = 0; i < 4; ++i)
#pragma unroll
                for (int j = 0; j < 4; ++j)
#pragma unroll
                    for (int ks = 0; ks < 2; ++ks)
                        acc[i][j] = __builtin_amdgcn_mfma_f32_16x16x32_f16(
                            afv[i][ks], bfv[j][ks], acc[i][j], 0, 0, 0);
            __builtin_amdgcn_s_setprio(0);
        }

        if constexpr (AF32) {
            writeA32(An, tid, 0, ga);          // cvt+ds_write first half (loads covered by ph0)
            loadA32(Ag32, tid, kn, 2, ga);     // issue second half (covered by ph1)
        }

        // ---- phase 1: m-fragments 4..7
        {
            half8_t afv[4][2];
#pragma unroll
            for (int i = 0; i < 4; ++i) {
                const int m = wr * 128 + (4 + i) * 16 + lrow;
#pragma unroll
                for (int ks = 0; ks < 2; ++ks)
                    afv[i][ks] = *(const half8_t*)(Ac + m * 64 + (((ks * 4 + kq) ^ (m & 7)) << 3));
            }
            __builtin_amdgcn_s_setprio(1);
#pragma unroll
            for (int i = 0; i < 4; ++i)
#pragma unroll
                for (int j = 0; j < 4; ++j)
#pragma unroll
                    for (int ks = 0; ks < 2; ++ks)
                        acc[4 + i][j] = __builtin_amdgcn_mfma_f32_16x16x32_f16(
                            afv[i][ks], bfv[j][ks], acc[4 + i][j], 0, 0, 0);
            __builtin_amdgcn_s_setprio(0);
        }

        if constexpr (AF32) {
            writeA32(An, tid, 2, ga);          // second half cvt+ds_write
        }
        // own ds ops (reads consumed, writes posted) complete, then sync:
        // after this barrier buf cur is free and (for AF32) buf nxt's A is valid.
        asm volatile("s_waitcnt lgkmcnt(0)" ::: "memory");
        __builtin_amdgcn_s_barrier();
    }
    // drain the dead last-iteration staging before the block can retire
    asm volatile("s_waitcnt vmcnt(0)" ::: "memory");

    // Epilogue (proven): C/D layout col=lane&15, row=(lane>>4)*4+reg
    const int ccol  = lane & 15;
    const int rbase = (lane >> 4) << 2;
#pragma unroll
    for (int j = 0; j < 4; ++j) {
        const int gcol = col0 + wc * 64 + j * 16 + ccol;
        const float bv = bias[gcol];
#pragma unroll
        for (int i = 0; i < 8; ++i) {
#pragma unroll
            for (int r = 0; r < 4; ++r) {
                const int grow = row0 + wr * 128 + i * 16 + rbase + r;
                C[(size_t)grow * N + gcol] = (TC)(acc[i][j][r] + bv);
            }
        }
    }
}

template <typename TA, typename TC>
__global__ __launch_bounds__(512, 2) void gemm_kernel(
    const TA* __restrict__ A, const float* __restrict__ bias,
    TC* __restrict__ C) {
    gemm_tile256<TA, TC>(A, bias, C);
}

// Fused q/k/v projection: same W, independent outputs; blockIdx.z selects pair.
__global__ __launch_bounds__(512, 2) void gemm_proj_kernel(
    const float* __restrict__ q, const float* __restrict__ k,
    const float* __restrict__ v, const float* __restrict__ bias,
    f16* __restrict__ cq, f16* __restrict__ ck, f16* __restrict__ cv) {
    const int z = blockIdx.z;
    const float* A = (z == 0) ? q : (z == 1) ? k : v;
    f16*         C = (z == 0) ? cq : (z == 1) ? ck : cv;
    gemm_tile256<float, f16>(A, bias, C);
}

// One wave per (b,s). lane = d owns a full softmax row (no cross-lane ops).
// K staged transposed [e][h] (rows padded to 24 halves), V straight [h][e]
// (rows padded to 72 halves).  QK and PV via v_dot2_f32_f16, f32 accum.
__global__ __launch_bounds__(256) void attn_kernel(
    const f16* __restrict__ pq, const f16* __restrict__ pk,
    const f16* __restrict__ pv, f16* __restrict__ outp)
{
    __shared__ __align__(16) f16 Ks[4][64][24];
    __shared__ __align__(16) f16 Vs[4][16][72];
    const int lane = threadIdx.x & 63;
    const int wave = threadIdx.x >> 6;
    const int p = blockIdx.x * 4 + wave;
    const int b = p >> 11;   // / 2048
    const int s = p & 2047;
    const f16* qptr = pq + (size_t)p * 1024;
    const f16* kptr = pk + (size_t)p * 1024;
    const f16* vptr = pv + (size_t)p * 1024;

    {
        const int h  = lane >> 2;
        const int e0 = (lane & 3) << 4;
        const half8_t k0 = *(const half8_t*)(kptr + lane * 16);
        const half8_t k1 = *(const half8_t*)(kptr + lane * 16 + 8);
#pragma unroll
        for (int t = 0; t < 8; ++t) {
            Ks[wave][e0 + t][h]     = k0[t];
            Ks[wave][e0 + 8 + t][h] = k1[t];
        }
        const half8_t v0 = *(const half8_t*)(vptr + lane * 16);
        const half8_t v1 = *(const half8_t*)(vptr + lane * 16 + 8);
        *(half8_t*)&Vs[wave][h][e0]     = v0;
        *(half8_t*)&Vs[wave][h][e0 + 8] = v1;
    }
    half2_t qp2[8];
#pragma unroll
    for (int h2 = 0; h2 < 8; ++h2) {
        half2_t t;
        t[0] = qptr[(2 * h2) * 64 + lane];
        t[1] = qptr[(2 * h2 + 1) * 64 + lane];
        qp2[h2] = t;
    }
    __syncthreads();

    float a[64];
#pragma unroll
    for (int e = 0; e < 64; ++e) {
        const half8_t* kr = (const half8_t*)&Ks[wave][e][0];
        const half8_t ka = kr[0];
        const half8_t kb = kr[1];
        float acc = 0.f;
#pragma unroll
        for (int t = 0; t < 4; ++t) {
            half2_t k2a; k2a[0] = ka[2 * t]; k2a[1] = ka[2 * t + 1];
            half2_t k2b; k2b[0] = kb[2 * t]; k2b[1] = kb[2 * t + 1];
            acc = fdot2(qp2[t], k2a, acc);
            acc = fdot2(qp2[4 + t], k2b, acc);
        }
        a[e] = acc;
    }

    float m = a[0];
#pragma unroll
    for (int e = 1; e < 64; ++e) m = fmaxf(m, a[e]);
    float sum = 0.f;
#pragma unroll
    for (int e = 0; e < 64; ++e) {
        const float t = __expf((a[e] - m) * 0.125f);
        a[e] = t;
        sum += t;
    }
    const float inv = 1.f / sum;

    half2_t pk2[32];
#pragma unroll
    for (int e2 = 0; e2 < 32; ++e2)
        pk2[e2] = pkrtz(a[2 * e2], a[2 * e2 + 1]);

    float o[16];
#pragma unroll
    for (int h = 0; h < 16; ++h) {
        const half8_t* vr = (const half8_t*)&Vs[wave][h][0];
        float acc = 0.f;
#pragma unroll
        for (int q8 = 0; q8 < 8; ++q8) {
            const half8_t vv = vr[q8];
#pragma unroll
            for (int t = 0; t < 4; ++t) {
                half2_t v2; v2[0] = vv[2 * t]; v2[1] = vv[2 * t + 1];
                acc = fdot2(pk2[q8 * 4 + t], v2, acc);
            }
        }
        o[h] = acc;
    }

    half8_t o0, o1;
#pragma unroll
    for (int h = 0; h < 8; ++h) o0[h] = (f16)(o[h] * inv);
#pragma unroll
    for (int h = 0; h < 8; ++h) o1[h] = (f16)(o[8 + h] * inv);
    f16* dst = outp + ((size_t)(b * 64 + lane) * 2048 + s) * 16;
    *(half8_t*)dst       = o0;
    *(half8_t*)(dst + 8) = o1;
}

extern "C" void kernel_launch(void* const* d_in, const int* in_sizes, int n_in,
                              void* d_out, int out_size, void* d_ws, size_t ws_size,
                              hipStream_t stream)
{
    const float* q    = (const float*)d_in[0];
    const float* k    = (const float*)d_in[1];
    const float* v    = (const float*)d_in[2];
    const float* W    = (const float*)d_in[3];
    const float* bias = (const float*)d_in[4];
    float* out = (float*)d_out;

    const int M = 16384;
    const size_t elems = (size_t)M * 1024;

    // ws: projq (32MB f16) + attn_out (32MB f16). projk/projv parked inside
    // d_out (64MB fp32), consumed by attn before the final GEMM overwrites it.
    f16* projq = (f16*)d_ws;
    f16* attn  = projq + elems;
    f16* projk = (f16*)d_out;
    f16* projv = projk + elems;

    convert_w_kernel<<<512, 256, 0, stream>>>(W);

    dim3 gridp(M / 256, 1024 / 256, 3);  // fused q/k/v projections
    gemm_proj_kernel<<<gridp, 512, 0, stream>>>(q, k, v, bias, projq, projk, projv);
    attn_kernel<<<M / 4, 256, 0, stream>>>(projq, projk, projv, attn);
    dim3 gridf(M / 256, 1024 / 256);
    gemm_kernel<f16, float><<<gridf, 512, 0, stream>>>(attn, bias, out);
}